// Round 20
// baseline (166.386 us; speedup 1.0000x reference)
//
#include <hip/hip_runtime.h>
#include <stddef.h>

#define N_NODES 10000
#define N_EDGES 160000
#define DIM     512
#define RBT     158           // 64-row tiles incl. one zero pad tile (10112 rows)
#define RB128   79            // 128-row blocks
#define GBLKS   (RB128 * 4)   // 316 gemm blocks
#define EBLKS   625
#define PAKBLKS (RBT * 16)    // 2528
#define MAXDEG  64            // P(Binomial(160000,1e-4) >= 64) ~ 1e-19 -- structurally safe

typedef short bf16x8 __attribute__((ext_vector_type(8)));
typedef float f32x4  __attribute__((ext_vector_type(4)));

__device__ inline unsigned short bf16_rne(float f) {
    unsigned u = __builtin_bit_cast(unsigned, f);
    u += 0x7FFF + ((u >> 16) & 1);
    return (unsigned short)(u >> 16);
}
__device__ inline float bf16_to_f32(unsigned short h) {
    unsigned u = ((unsigned)h) << 16;
    return __builtin_bit_cast(float, u);
}

__device__ inline void gld_lds16(const void* g, void* lds) {
    __builtin_amdgcn_global_load_lds(
        (const __attribute__((address_space(1))) void*)g,
        (__attribute__((address_space(3))) void*)lds, 16, 0, 0);
}

// bf16 relu on packed shorts: bf16 sign bit == int16 sign => max_i16(v,0) is exact relu
__device__ __forceinline__ bf16x8 relu_pk(bf16x8 v) {
    bf16x8 r;
#pragma unroll
    for (int i = 0; i < 8; ++i) r[i] = (v[i] < (short)0) ? (short)0 : v[i];
    return r;
}

// ================= merged prep: pack 4 weights + pack x + count deg =================
// deg+cursor zeroed by one hipMemsetAsync before this kernel.
// Tile layout (shorts): [blk64][kt 16][idx 64][k 32], 2048/tile; XOR perm baked.

__global__ __launch_bounds__(256) void prep_kernel(
    const float* __restrict__ W1, const float* __restrict__ W2,
    const float* __restrict__ Wp1, const float* __restrict__ Wp2,
    short* __restrict__ T1, short* __restrict__ T2,
    short* __restrict__ Tp1, short* __restrict__ Tp2,
    const float* __restrict__ X, short* __restrict__ APKx,
    const int* __restrict__ ei, int* __restrict__ deg)
{
    const int bid = blockIdx.x;
    if (bid < 512) {                       // ---- pack weights ----
        const int wsel = bid >> 7;
        const float* W = (wsel == 0) ? W1 : (wsel == 1) ? W2 : (wsel == 2) ? Wp1 : Wp2;
        short* WT      = (wsel == 0) ? T1 : (wsel == 1) ? T2 : (wsel == 2) ? Tp1 : Tp2;
        int id = (bid & 127) * 256 + threadIdx.x;
        int n  = id & 511;
        int kc = id >> 9;
        int colblk = n >> 6, col = n & 63;
        int kt = kc >> 2, kq = kc & 3;
        short hi[8];
#pragma unroll
        for (int j = 0; j < 8; ++j)
            hi[j] = (short)bf16_rne(W[(size_t)(kc * 8 + j) * 512 + n]);
        size_t base = (size_t)(colblk * 16 + kt) * 2048 + col * 32 + ((kq ^ ((col >> 1) & 3)) << 3);
        *(int4*)(WT + base) = *(const int4*)hi;
    } else if (bid < 512 + PAKBLKS) {      // ---- pack x ----
        const int pb = bid - 512;
        const int kt = pb & 15;
        const int rb = pb >> 4;
        const int t  = threadIdx.x;
        const int r  = t >> 2;
        const int kq = t & 3;
        const int row = rb * 64 + r;
        float v[8] = {};
        if (row < N_NODES) {
            float4 a = *(const float4*)(X + (size_t)row * 512 + kt * 32 + kq * 8);
            float4 b = *(const float4*)(X + (size_t)row * 512 + kt * 32 + kq * 8 + 4);
            v[0]=a.x; v[1]=a.y; v[2]=a.z; v[3]=a.w; v[4]=b.x; v[5]=b.y; v[6]=b.z; v[7]=b.w;
        }
        short hi[8];
#pragma unroll
        for (int j = 0; j < 8; ++j) hi[j] = (short)bf16_rne(v[j]);
        size_t base = (size_t)(rb * 16 + kt) * 2048 + r * 32 + ((kq ^ ((r >> 1) & 3)) << 3);
        *(int4*)(APKx + base) = *(const int4*)hi;
    } else {                               // ---- count deg ----
        int e = (bid - 512 - PAKBLKS) * 256 + threadIdx.x;
        if (e < N_EDGES) atomicAdd(&deg[ei[N_EDGES + e]], 1);
    }
}

// ================= standalone scatter (fixed-stride int2 CSR) =================

__global__ __launch_bounds__(256) void scatter_kernel(
    const int* __restrict__ ei, const int* __restrict__ deg,
    int* __restrict__ cursor, int2* __restrict__ csr)
{
    int e = blockIdx.x * 256 + threadIdx.x;
    if (e >= N_EDGES) return;
    int s = ei[e];
    int d = ei[N_EDGES + e];
    int slot = d * MAXDEG + atomicAdd(&cursor[d], 1);
    float nrm = rsqrtf((float)(deg[s] + 1)) * rsqrtf((float)(deg[d] + 1));
    csr[slot] = make_int2(s, __float_as_int(nrm));
}

// ================= 128x128 bf16 LDS-staged GEMM core =================
// 4 waves (2x2); 3-deep circular buffer, ONE barrier per kt, counted vmcnt(4).
// rb-chunked 2D XCD map (cb fastest): A panels enter exactly one XCD's L2.

__device__ __forceinline__ void map_block(int bid, int& rb, int& cb) {
    const int q = GBLKS / 8;      // 39
    const int r = GBLKS % 8;      // 4
    int xcd = bid & 7;
    int idx = bid >> 3;
    int L = (xcd < r ? xcd * (q + 1) : r * (q + 1) + (xcd - r) * q) + idx;
    rb = L >> 2;                  // cb fastest -> A reuse within XCD
    cb = L & 3;
}

template<bool RELU_A>
__device__ __forceinline__ void gemm128_core(
    const short* __restrict__ Apk, const short* __restrict__ Wpk,
    int bid, f32x4 (&acc)[4][4],
    short (*As)[4096], short (*Bs)[4096],   // [3][4096]
    int& rb, int& cb, int& wr, int& wc)
{
    map_block(bid, rb, cb);
    const int tid = threadIdx.x;
    const int w = tid >> 6;
    wr = w >> 1;
    wc = w & 1;
    const int lane = tid & 63;
    const int l15 = lane & 15, kg = lane >> 4;
    const int kso = ((kg ^ ((l15 >> 1) & 3)) << 3);
    const int wofs = w * 1024;

    const char* At0 = (const char*)(Apk + (size_t)(rb * 2)     * 16 * 2048);
    const char* At1 = (const char*)(Apk + (size_t)(rb * 2 + 1) * 16 * 2048);
    const char* Bt0 = (const char*)(Wpk + (size_t)(cb * 2)     * 16 * 2048);
    const char* Bt1 = (const char*)(Wpk + (size_t)(cb * 2 + 1) * 16 * 2048);

#pragma unroll
    for (int i = 0; i < 4; ++i)
#pragma unroll
        for (int j = 0; j < 4; ++j) acc[i][j] = (f32x4){0.f, 0.f, 0.f, 0.f};

    auto stage = [&](int buf, int kt) {
        const int go = kt * 4096 + tid * 16;
        char* ad = (char*)&As[buf][0];
        char* bd = (char*)&Bs[buf][0];
        gld_lds16(At0 + go, ad + wofs);
        gld_lds16(At1 + go, ad + 4096 + wofs);
        gld_lds16(Bt0 + go, bd + wofs);
        gld_lds16(Bt1 + go, bd + 4096 + wofs);
    };

    stage(0, 0);
    stage(1, 1);

#pragma unroll
    for (int kt = 0; kt < 16; ++kt) {
        const int buf = kt % 3;
        if (kt < 15) {
            asm volatile("s_waitcnt vmcnt(4)" ::: "memory");   // tile kt landed; kt+1 in flight
        } else {
            asm volatile("s_waitcnt vmcnt(0)" ::: "memory");
        }
        __builtin_amdgcn_s_barrier();
        __builtin_amdgcn_sched_barrier(0);
        if (kt < 14) stage((kt + 2) % 3, kt + 2);

        const short* as = &As[buf][wr * 2048];
        const short* bs = &Bs[buf][wc * 2048];
        bf16x8 af[4], bf[4];
#pragma unroll
        for (int m = 0; m < 4; ++m) {
            af[m] = *(const bf16x8*)&as[(m * 16 + l15) * 32 + kso];
            if (RELU_A) af[m] = relu_pk(af[m]);
        }
#pragma unroll
        for (int n = 0; n < 4; ++n)
            bf[n] = *(const bf16x8*)&bs[(n * 16 + l15) * 32 + kso];
#pragma unroll
        for (int m = 0; m < 4; ++m)
#pragma unroll
            for (int n = 0; n < 4; ++n)
                acc[m][n] = __builtin_amdgcn_mfma_f32_16x16x32_bf16(af[m], bf[n], acc[m][n], 0, 0, 0);
    }
}

// ---- epilogues ----

template<bool RELU_OUT>
__device__ __forceinline__ void epi128_f32(f32x4 (&acc)[4][4], const float* bias,
                                           float* C, int rb, int cb, int wr, int wc) {
    const int lane = threadIdx.x & 63;
    const int l15 = lane & 15, kg = lane >> 4;
#pragma unroll
    for (int n = 0; n < 4; ++n) {
        int c = cb * 128 + wc * 64 + n * 16 + l15;
        float bv = bias[c];
#pragma unroll
        for (int m = 0; m < 4; ++m) {
            int r0 = rb * 128 + wr * 64 + m * 16 + kg * 4;
#pragma unroll
            for (int j = 0; j < 4; ++j) {
                int row = r0 + j;
                if (row < N_NODES) {
                    float v = acc[m][n][j] + bv;
                    if (RELU_OUT) v = fmaxf(v, 0.f);
                    C[(size_t)row * 512 + c] = v;
                }
            }
        }
    }
}

__device__ __forceinline__ void epi128_bf16(f32x4 (&acc)[4][4], const float* bias,
                                            unsigned short* C, int rb, int cb, int wr, int wc) {
    const int lane = threadIdx.x & 63;
    const int l15 = lane & 15, kg = lane >> 4;
#pragma unroll
    for (int n = 0; n < 4; ++n) {
        int c = cb * 128 + wc * 64 + n * 16 + l15;
        float bv = bias[c];
#pragma unroll
        for (int m = 0; m < 4; ++m) {
            int r0 = rb * 128 + wr * 64 + m * 16 + kg * 4;
#pragma unroll
            for (int j = 0; j < 4; ++j) {
                int row = r0 + j;
                if (row < N_NODES)
                    C[(size_t)row * 512 + c] = bf16_rne(acc[m][n][j] + bv);
            }
        }
    }
}

// relu(acc+bias) -> packed bf16 A-layout for the next GEMM
__device__ __forceinline__ void epi128_pack(f32x4 (&acc)[4][4], const float* bias,
                                            short* Cpk, int rb, int cb, int wr, int wc) {
    const int lane = threadIdx.x & 63;
    const int l15 = lane & 15, kg = lane >> 4;
#pragma unroll
    for (int n = 0; n < 4; ++n) {
        int c = cb * 128 + wc * 64 + n * 16 + l15;   // = next-gemm k index
        int kt_n = c >> 5, kk = c & 31, kgn = kk >> 3, kj = kk & 7;
        float bv = bias[c];
#pragma unroll
        for (int m = 0; m < 4; ++m) {
#pragma unroll
            for (int j = 0; j < 4; ++j) {
                int grow = rb * 128 + wr * 64 + m * 16 + kg * 4 + j;   // <= 10111
                float v = (grow < N_NODES) ? fmaxf(acc[m][n][j] + bv, 0.f) : 0.f;
                int rt = grow >> 6, rl = grow & 63;
                size_t dst = (size_t)(rt * 16 + kt_n) * 2048 + rl * 32
                           + ((kgn ^ ((rl >> 1) & 3)) << 3) + kj;
                Cpk[dst] = (short)bf16_rne(v);
            }
        }
    }
}

// ================= GEMM1 (pure) =================

__global__ __launch_bounds__(256, 3) void gemm1_kernel(
    const short* __restrict__ APKx, const short* __restrict__ WT1,
    const float* __restrict__ b1, unsigned short* __restrict__ Hb)
{
    __shared__ short As[3][4096];
    __shared__ short Bs[3][4096];
    f32x4 acc[4][4];
    int rb, cb, wr, wc;
    gemm128_core<false>(APKx, WT1, blockIdx.x, acc, As, Bs, rb, cb, wr, wc);
    epi128_bf16(acc, b1, Hb, rb, cb, wr, wc);
}

// ================= aggregate1 + fused z-pack (2 nodes/block, ushort4) =================
// grid 5056 covers 10112 rows (pad rows write zero ZPKp)

__global__ __launch_bounds__(256) void agg1_pack_kernel(
    const unsigned short* __restrict__ Hb,
    const int* __restrict__ deg,
    const int2* __restrict__ csr,
    float* __restrict__ z,
    short* __restrict__ ZPKp)
{
    const int node = blockIdx.x * 2 + (threadIdx.x >> 7);
    const int q = threadIdx.x & 127;
    const int f0 = q * 4;
    const int kt = f0 >> 5, kq = (f0 >> 3) & 3, j = f0 & 7;   // j in {0,4}
    const int rb = node >> 6, r = node & 63;
    const size_t dst = (size_t)(rb * 16 + kt) * 2048 + r * 32 + ((kq ^ ((r >> 1) & 3)) << 3) + j;

    if (node >= N_NODES) {   // zero pad rows
        *(ushort4*)(ZPKp + dst) = make_ushort4(0, 0, 0, 0);
        return;
    }

    const int base = node * MAXDEG;
    const int end  = base + deg[node];
    const float dn = rsqrtf((float)(deg[node] + 1));
    const float sw = dn * dn;

    ushort4 hv = *((const ushort4*)(Hb + (size_t)node * DIM) + q);
    float a0 = bf16_to_f32(hv.x) * sw;
    float a1 = bf16_to_f32(hv.y) * sw;
    float a2 = bf16_to_f32(hv.z) * sw;
    float a3 = bf16_to_f32(hv.w) * sw;

    int e = base;
    for (; e + 7 < end; e += 8) {
        int s[8]; float w[8]; ushort4 v[8];
#pragma unroll
        for (int i = 0; i < 8; ++i) {
            int2 c = csr[e + i];
            s[i] = c.x;
            w[i] = __int_as_float(c.y);
        }
#pragma unroll
        for (int i = 0; i < 8; ++i) v[i] = *((const ushort4*)(Hb + (size_t)s[i] * DIM) + q);
#pragma unroll
        for (int i = 0; i < 8; ++i) {
            a0 += bf16_to_f32(v[i].x) * w[i];
            a1 += bf16_to_f32(v[i].y) * w[i];
            a2 += bf16_to_f32(v[i].z) * w[i];
            a3 += bf16_to_f32(v[i].w) * w[i];
        }
    }
    for (; e < end; ++e) {
        int2 c = csr[e];
        float wi = __int_as_float(c.y);
        ushort4 vi = *((const ushort4*)(Hb + (size_t)c.x * DIM) + q);
        a0 += bf16_to_f32(vi.x) * wi;
        a1 += bf16_to_f32(vi.y) * wi;
        a2 += bf16_to_f32(vi.z) * wi;
        a3 += bf16_to_f32(vi.w) * wi;
    }
    *((float4*)(z + (size_t)node * DIM) + q) = make_float4(a0, a1, a2, a3);
    *(ushort4*)(ZPKp + dst) = make_ushort4(bf16_rne(a0), bf16_rne(a1), bf16_rne(a2), bf16_rne(a3));
}

// ================= fused GEMM2 || GEMM3 (both read ZPKp; GEMM2 relus A in-reg) =================

__global__ __launch_bounds__(256, 3) void gemm23_kernel(
    const short* __restrict__ ZPKp, const short* __restrict__ WT2,
    const float* __restrict__ b2, unsigned short* __restrict__ Hb,
    const short* __restrict__ WTp1,
    const float* __restrict__ bp1, short* __restrict__ APKp1)
{
    __shared__ short As[3][4096];
    __shared__ short Bs[3][4096];
    const int bid = blockIdx.x;
    f32x4 acc[4][4];
    int rb, cb, wr, wc;
    if (bid < GBLKS) {
        gemm128_core<true>(ZPKp, WT2, bid, acc, As, Bs, rb, cb, wr, wc);   // relu(z)@W2
        epi128_bf16(acc, b2, Hb, rb, cb, wr, wc);
    } else {
        gemm128_core<false>(ZPKp, WTp1, bid - GBLKS, acc, As, Bs, rb, cb, wr, wc);  // z@Wp1
        epi128_pack(acc, bp1, APKp1, rb, cb, wr, wc);
    }
}

// ================= aggregate2 (2 nodes/block, ushort4) =================

__global__ __launch_bounds__(256) void agg2_kernel(
    const unsigned short* __restrict__ Hb,
    const int* __restrict__ deg,
    const int2* __restrict__ csr,
    float* __restrict__ out)
{
    const int node = blockIdx.x * 2 + (threadIdx.x >> 7);
    const int q = threadIdx.x & 127;

    const int base = node * MAXDEG;
    const int end  = base + deg[node];
    const float dn = rsqrtf((float)(deg[node] + 1));
    const float sw = dn * dn;

    ushort4 hv = *((const ushort4*)(Hb + (size_t)node * DIM) + q);
    float a0 = bf16_to_f32(hv.x) * sw;
    float a1 = bf16_to_f32(hv.y) * sw;
    float a2 = bf16_to_f32(hv.z) * sw;
    float a3 = bf16_to_f32(hv.w) * sw;

    int e = base;
    for (; e + 7 < end; e += 8) {
        int s[8]; float w[8]; ushort4 v[8];
#pragma unroll
        for (int i = 0; i < 8; ++i) {
            int2 c = csr[e + i];
            s[i] = c.x;
            w[i] = __int_as_float(c.y);
        }
#pragma unroll
        for (int i = 0; i < 8; ++i) v[i] = *((const ushort4*)(Hb + (size_t)s[i] * DIM) + q);
#pragma unroll
        for (int i = 0; i < 8; ++i) {
            a0 += bf16_to_f32(v[i].x) * w[i];
            a1 += bf16_to_f32(v[i].y) * w[i];
            a2 += bf16_to_f32(v[i].z) * w[i];
            a3 += bf16_to_f32(v[i].w) * w[i];
        }
    }
    for (; e < end; ++e) {
        int2 c = csr[e];
        float wi = __int_as_float(c.y);
        ushort4 vi = *((const ushort4*)(Hb + (size_t)c.x * DIM) + q);
        a0 += bf16_to_f32(vi.x) * wi;
        a1 += bf16_to_f32(vi.y) * wi;
        a2 += bf16_to_f32(vi.z) * wi;
        a3 += bf16_to_f32(vi.w) * wi;
    }
    *((float4*)(out + (size_t)node * DIM) + q) = make_float4(a0, a1, a2, a3);
}

// ================= GEMM4 =================

__global__ __launch_bounds__(256, 3) void gemm4_kernel(
    const short* __restrict__ APKp1, const short* __restrict__ WTp2,
    const float* __restrict__ bp2, float* __restrict__ proj)
{
    __shared__ short As[3][4096];
    __shared__ short Bs[3][4096];
    f32x4 acc[4][4];
    int rb, cb, wr, wc;
    gemm128_core<false>(APKp1, WTp2, blockIdx.x, acc, As, Bs, rb, cb, wr, wc);
    epi128_f32<false>(acc, bp2, proj, rb, cb, wr, wc);
}

// ================= launch =================

extern "C" void kernel_launch(void* const* d_in, const int* in_sizes, int n_in,
                              void* d_out, int out_size, void* d_ws, size_t ws_size,
                              hipStream_t stream) {
    const float* x   = (const float*)d_in[0];
    const int*   ei  = (const int*)d_in[1];
    const float* W1  = (const float*)d_in[2];
    const float* b1  = (const float*)d_in[3];
    const float* W2  = (const float*)d_in[4];
    const float* b2  = (const float*)d_in[5];
    const float* Wp1 = (const float*)d_in[6];
    const float* bp1 = (const float*)d_in[7];
    const float* Wp2 = (const float*)d_in[8];
    const float* bp2 = (const float*)d_in[9];

    float* out  = (float*)d_out;
    float* z    = out + (size_t)N_NODES * DIM;
    float* proj = z   + (size_t)N_NODES * DIM;

    char* ws = (char*)d_ws;
    size_t off = 0;
    auto walloc = [&](size_t bytes) -> void* {
        void* p = ws + off;
        off = (off + bytes + 255) & ~(size_t)255;
        return p;
    };
    const size_t PK_SHORTS = (size_t)RBT * 16 * 2048;   // 10.35 MB
    unsigned short* Hb = (unsigned short*)walloc((size_t)N_NODES * DIM * sizeof(unsigned short));
    short* APKx  = (short*)walloc(PK_SHORTS * sizeof(short));
    short* ZPKp  = (short*)walloc(PK_SHORTS * sizeof(short));
    short* APKp1 = (short*)walloc(PK_SHORTS * sizeof(short));
    short* WT1  = (short*)walloc((size_t)8 * 16 * 2048 * sizeof(short));
    short* WT2  = (short*)walloc((size_t)8 * 16 * 2048 * sizeof(short));
    short* WTp1 = (short*)walloc((size_t)8 * 16 * 2048 * sizeof(short));
    short* WTp2 = (short*)walloc((size_t)8 * 16 * 2048 * sizeof(short));
    int*   degcur   = (int*)  walloc((size_t)2 * N_NODES * sizeof(int));  // deg | cursor, one memset
    int*   deg      = degcur;
    int*   cursor   = degcur + N_NODES;
    int2*  csr      = (int2*) walloc((size_t)N_NODES * MAXDEG * sizeof(int2));  // 5.12 MB

    const dim3 blk(256);

    hipMemsetAsync(degcur, 0, (size_t)2 * N_NODES * sizeof(int), stream);
    prep_kernel<<<dim3(512 + PAKBLKS + EBLKS), blk, 0, stream>>>(
        W1, W2, Wp1, Wp2, WT1, WT2, WTp1, WTp2, x, APKx, ei, deg);
    scatter_kernel<<<dim3(EBLKS), blk, 0, stream>>>(ei, deg, cursor, csr);

    gemm1_kernel<<<dim3(GBLKS), blk, 0, stream>>>(APKx, WT1, b1, Hb);
    agg1_pack_kernel<<<dim3(RB128 * 64), blk, 0, stream>>>(
        Hb, deg, csr, z, ZPKp);
    gemm23_kernel<<<dim3(2 * GBLKS), blk, 0, stream>>>(
        ZPKp, WT2, b2, Hb, WTp1, bp1, APKp1);
    agg2_kernel<<<dim3(N_NODES / 2), blk, 0, stream>>>(
        Hb, deg, csr, out);
    gemm4_kernel<<<dim3(GBLKS), blk, 0, stream>>>(APKp1, WTp2, bp2, proj);
}

// Round 21
// 146.505 us; speedup vs baseline: 1.1357x; 1.1357x over previous
//
#include <hip/hip_runtime.h>
#include <stddef.h>

#define N_NODES 10000
#define N_EDGES 160000
#define DIM     512
#define RBT     158           // 64-row tiles incl. one zero pad tile (10112 rows)
#define RB128   79            // 128-row blocks
#define GBLKS   (RB128 * 4)   // 316 gemm blocks
#define EBLKS   625
#define PAKBLKS (RBT * 16)    // 2528
#define MAXDEG  64            // P(Binomial(160000,1e-4) >= 64) ~ 1e-19 -- structurally safe

typedef short bf16x8 __attribute__((ext_vector_type(8)));
typedef float f32x4  __attribute__((ext_vector_type(4)));

__device__ inline unsigned short bf16_rne(float f) {
    unsigned u = __builtin_bit_cast(unsigned, f);
    u += 0x7FFF + ((u >> 16) & 1);
    return (unsigned short)(u >> 16);
}
__device__ inline float bf16_to_f32(unsigned short h) {
    unsigned u = ((unsigned)h) << 16;
    return __builtin_bit_cast(float, u);
}

__device__ inline void gld_lds16(const void* g, void* lds) {
    __builtin_amdgcn_global_load_lds(
        (const __attribute__((address_space(1))) void*)g,
        (__attribute__((address_space(3))) void*)lds, 16, 0, 0);
}

// bf16 relu on packed shorts: bf16 sign bit == int16 sign => max_i16(v,0) is exact relu
__device__ __forceinline__ bf16x8 relu_pk(bf16x8 v) {
    bf16x8 r;
#pragma unroll
    for (int i = 0; i < 8; ++i) r[i] = (v[i] < (short)0) ? (short)0 : v[i];
    return r;
}

// ================= merged prep: pack 4 weights + pack x + count deg =================
// deg zeroed by hipMemsetAsync before this kernel.
// Tile layout (shorts): [blk64][kt 16][idx 64][k 32], 2048/tile; XOR perm baked.

__global__ __launch_bounds__(256) void prep_kernel(
    const float* __restrict__ W1, const float* __restrict__ W2,
    const float* __restrict__ Wp1, const float* __restrict__ Wp2,
    short* __restrict__ T1, short* __restrict__ T2,
    short* __restrict__ Tp1, short* __restrict__ Tp2,
    const float* __restrict__ X, short* __restrict__ APKx,
    const int* __restrict__ ei, int* __restrict__ deg)
{
    const int bid = blockIdx.x;
    if (bid < 512) {                       // ---- pack weights ----
        const int wsel = bid >> 7;
        const float* W = (wsel == 0) ? W1 : (wsel == 1) ? W2 : (wsel == 2) ? Wp1 : Wp2;
        short* WT      = (wsel == 0) ? T1 : (wsel == 1) ? T2 : (wsel == 2) ? Tp1 : Tp2;
        int id = (bid & 127) * 256 + threadIdx.x;
        int n  = id & 511;
        int kc = id >> 9;
        int colblk = n >> 6, col = n & 63;
        int kt = kc >> 2, kq = kc & 3;
        short hi[8];
#pragma unroll
        for (int j = 0; j < 8; ++j)
            hi[j] = (short)bf16_rne(W[(size_t)(kc * 8 + j) * 512 + n]);
        size_t base = (size_t)(colblk * 16 + kt) * 2048 + col * 32 + ((kq ^ ((col >> 1) & 3)) << 3);
        *(int4*)(WT + base) = *(const int4*)hi;
    } else if (bid < 512 + PAKBLKS) {      // ---- pack x ----
        const int pb = bid - 512;
        const int kt = pb & 15;
        const int rb = pb >> 4;
        const int t  = threadIdx.x;
        const int r  = t >> 2;
        const int kq = t & 3;
        const int row = rb * 64 + r;
        float v[8] = {};
        if (row < N_NODES) {
            float4 a = *(const float4*)(X + (size_t)row * 512 + kt * 32 + kq * 8);
            float4 b = *(const float4*)(X + (size_t)row * 512 + kt * 32 + kq * 8 + 4);
            v[0]=a.x; v[1]=a.y; v[2]=a.z; v[3]=a.w; v[4]=b.x; v[5]=b.y; v[6]=b.z; v[7]=b.w;
        }
        short hi[8];
#pragma unroll
        for (int j = 0; j < 8; ++j) hi[j] = (short)bf16_rne(v[j]);
        size_t base = (size_t)(rb * 16 + kt) * 2048 + r * 32 + ((kq ^ ((r >> 1) & 3)) << 3);
        *(int4*)(APKx + base) = *(const int4*)hi;
    } else {                               // ---- count deg ----
        int e = (bid - 512 - PAKBLKS) * 256 + threadIdx.x;
        if (e < N_EDGES) atomicAdd(&deg[ei[N_EDGES + e]], 1);
    }
}

// ================= deg -> dis, zero cursor =================

__global__ __launch_bounds__(256) void deg2dis_kernel(const int* __restrict__ deg,
                                                      float* __restrict__ dis,
                                                      int* __restrict__ cursor, int n) {
    int i = blockIdx.x * 256 + threadIdx.x;
    if (i < n) {
        dis[i] = rsqrtf((float)(deg[i] + 1));
        cursor[i] = 0;
    }
}

// ================= 128x128 bf16 LDS-staged GEMM core =================
// 4 waves (2x2); 3-deep circular buffer, ONE barrier per kt, counted vmcnt(4).
// rb-chunked 2D XCD map (cb fastest): A panels enter exactly one XCD's L2.

__device__ __forceinline__ void map_block(int bid, int& rb, int& cb) {
    const int q = GBLKS / 8;      // 39
    const int r = GBLKS % 8;      // 4
    int xcd = bid & 7;
    int idx = bid >> 3;
    int L = (xcd < r ? xcd * (q + 1) : r * (q + 1) + (xcd - r) * q) + idx;
    rb = L >> 2;                  // cb fastest -> A reuse within XCD
    cb = L & 3;
}

template<bool RELU_A>
__device__ __forceinline__ void gemm128_core(
    const short* __restrict__ Apk, const short* __restrict__ Wpk,
    int bid, f32x4 (&acc)[4][4],
    short (*As)[4096], short (*Bs)[4096],   // [3][4096]
    int& rb, int& cb, int& wr, int& wc)
{
    map_block(bid, rb, cb);
    const int tid = threadIdx.x;
    const int w = tid >> 6;
    wr = w >> 1;
    wc = w & 1;
    const int lane = tid & 63;
    const int l15 = lane & 15, kg = lane >> 4;
    const int kso = ((kg ^ ((l15 >> 1) & 3)) << 3);
    const int wofs = w * 1024;

    const char* At0 = (const char*)(Apk + (size_t)(rb * 2)     * 16 * 2048);
    const char* At1 = (const char*)(Apk + (size_t)(rb * 2 + 1) * 16 * 2048);
    const char* Bt0 = (const char*)(Wpk + (size_t)(cb * 2)     * 16 * 2048);
    const char* Bt1 = (const char*)(Wpk + (size_t)(cb * 2 + 1) * 16 * 2048);

#pragma unroll
    for (int i = 0; i < 4; ++i)
#pragma unroll
        for (int j = 0; j < 4; ++j) acc[i][j] = (f32x4){0.f, 0.f, 0.f, 0.f};

    auto stage = [&](int buf, int kt) {
        const int go = kt * 4096 + tid * 16;
        char* ad = (char*)&As[buf][0];
        char* bd = (char*)&Bs[buf][0];
        gld_lds16(At0 + go, ad + wofs);
        gld_lds16(At1 + go, ad + 4096 + wofs);
        gld_lds16(Bt0 + go, bd + wofs);
        gld_lds16(Bt1 + go, bd + 4096 + wofs);
    };

    stage(0, 0);
    stage(1, 1);

#pragma unroll
    for (int kt = 0; kt < 16; ++kt) {
        const int buf = kt % 3;
        if (kt < 15) {
            asm volatile("s_waitcnt vmcnt(4)" ::: "memory");   // tile kt landed; kt+1 in flight
        } else {
            asm volatile("s_waitcnt vmcnt(0)" ::: "memory");
        }
        __builtin_amdgcn_s_barrier();
        __builtin_amdgcn_sched_barrier(0);
        if (kt < 14) stage((kt + 2) % 3, kt + 2);

        const short* as = &As[buf][wr * 2048];
        const short* bs = &Bs[buf][wc * 2048];
        bf16x8 af[4], bf[4];
#pragma unroll
        for (int m = 0; m < 4; ++m) {
            af[m] = *(const bf16x8*)&as[(m * 16 + l15) * 32 + kso];
            if (RELU_A) af[m] = relu_pk(af[m]);
        }
#pragma unroll
        for (int n = 0; n < 4; ++n)
            bf[n] = *(const bf16x8*)&bs[(n * 16 + l15) * 32 + kso];
#pragma unroll
        for (int m = 0; m < 4; ++m)
#pragma unroll
            for (int n = 0; n < 4; ++n)
                acc[m][n] = __builtin_amdgcn_mfma_f32_16x16x32_bf16(af[m], bf[n], acc[m][n], 0, 0, 0);
    }
}

// ---- epilogues ----

template<bool RELU_OUT>
__device__ __forceinline__ void epi128_f32(f32x4 (&acc)[4][4], const float* bias,
                                           float* C, int rb, int cb, int wr, int wc) {
    const int lane = threadIdx.x & 63;
    const int l15 = lane & 15, kg = lane >> 4;
#pragma unroll
    for (int n = 0; n < 4; ++n) {
        int c = cb * 128 + wc * 64 + n * 16 + l15;
        float bv = bias[c];
#pragma unroll
        for (int m = 0; m < 4; ++m) {
            int r0 = rb * 128 + wr * 64 + m * 16 + kg * 4;
#pragma unroll
            for (int j = 0; j < 4; ++j) {
                int row = r0 + j;
                if (row < N_NODES) {
                    float v = acc[m][n][j] + bv;
                    if (RELU_OUT) v = fmaxf(v, 0.f);
                    C[(size_t)row * 512 + c] = v;
                }
            }
        }
    }
}

__device__ __forceinline__ void epi128_bf16(f32x4 (&acc)[4][4], const float* bias,
                                            unsigned short* C, int rb, int cb, int wr, int wc) {
    const int lane = threadIdx.x & 63;
    const int l15 = lane & 15, kg = lane >> 4;
#pragma unroll
    for (int n = 0; n < 4; ++n) {
        int c = cb * 128 + wc * 64 + n * 16 + l15;
        float bv = bias[c];
#pragma unroll
        for (int m = 0; m < 4; ++m) {
            int r0 = rb * 128 + wr * 64 + m * 16 + kg * 4;
#pragma unroll
            for (int j = 0; j < 4; ++j) {
                int row = r0 + j;
                if (row < N_NODES)
                    C[(size_t)row * 512 + c] = bf16_rne(acc[m][n][j] + bv);
            }
        }
    }
}

// relu(acc+bias) -> packed bf16 A-layout for the next GEMM
__device__ __forceinline__ void epi128_pack(f32x4 (&acc)[4][4], const float* bias,
                                            short* Cpk, int rb, int cb, int wr, int wc) {
    const int lane = threadIdx.x & 63;
    const int l15 = lane & 15, kg = lane >> 4;
#pragma unroll
    for (int n = 0; n < 4; ++n) {
        int c = cb * 128 + wc * 64 + n * 16 + l15;   // = next-gemm k index
        int kt_n = c >> 5, kk = c & 31, kgn = kk >> 3, kj = kk & 7;
        float bv = bias[c];
#pragma unroll
        for (int m = 0; m < 4; ++m) {
#pragma unroll
            for (int j = 0; j < 4; ++j) {
                int grow = rb * 128 + wr * 64 + m * 16 + kg * 4 + j;   // <= 10111
                float v = (grow < N_NODES) ? fmaxf(acc[m][n][j] + bv, 0.f) : 0.f;
                int rt = grow >> 6, rl = grow & 63;
                size_t dst = (size_t)(rt * 16 + kt_n) * 2048 + rl * 32
                           + ((kgn ^ ((rl >> 1) & 3)) << 3) + kj;
                Cpk[dst] = (short)bf16_rne(v);
            }
        }
    }
}

// ================= fused GEMM1 + scatter (fixed-stride CSR) =================

__global__ __launch_bounds__(256, 3) void gemm1_scatter_kernel(
    const short* __restrict__ APKx, const short* __restrict__ WT1,
    const float* __restrict__ b1, unsigned short* __restrict__ Hb,
    const int* __restrict__ ei, const float* __restrict__ dis,
    int* __restrict__ cursor,
    int* __restrict__ csr_src, float* __restrict__ csr_norm)
{
    __shared__ short As[3][4096];
    __shared__ short Bs[3][4096];
    const int bid = blockIdx.x;
    if (bid >= GBLKS) {
        int e = (bid - GBLKS) * 256 + threadIdx.x;
        if (e < N_EDGES) {
            int s = ei[e];
            int d = ei[N_EDGES + e];
            int slot = d * MAXDEG + atomicAdd(&cursor[d], 1);
            csr_src[slot]  = s;
            csr_norm[slot] = dis[s] * dis[d];
        }
        return;
    }
    f32x4 acc[4][4];
    int rb, cb, wr, wc;
    gemm128_core<false>(APKx, WT1, bid, acc, As, Bs, rb, cb, wr, wc);
    epi128_bf16(acc, b1, Hb, rb, cb, wr, wc);
}

// ================= aggregate1 + fused z-pack (2 nodes/block, ushort4 gathers) =================
// grid 5056 covers 10112 rows (pad rows write zero ZPKp)

__global__ __launch_bounds__(256) void agg1_pack_kernel(
    const unsigned short* __restrict__ Hb,
    const float* __restrict__ dis,
    const int* __restrict__ deg,
    const int* __restrict__ csr_src,
    const float* __restrict__ csr_norm,
    float* __restrict__ z,
    short* __restrict__ ZPKp)
{
    const int node = blockIdx.x * 2 + (threadIdx.x >> 7);
    const int q = threadIdx.x & 127;
    const int f0 = q * 4;
    const int kt = f0 >> 5, kq = (f0 >> 3) & 3, j = f0 & 7;   // j in {0,4}
    const int rb = node >> 6, r = node & 63;
    const size_t dst = (size_t)(rb * 16 + kt) * 2048 + r * 32 + ((kq ^ ((r >> 1) & 3)) << 3) + j;

    if (node >= N_NODES) {   // zero pad rows
        *(ushort4*)(ZPKp + dst) = make_ushort4(0, 0, 0, 0);
        return;
    }

    const int base = node * MAXDEG;
    const int end  = base + deg[node];
    const float dn = dis[node];
    const float sw = dn * dn;

    ushort4 hv = *((const ushort4*)(Hb + (size_t)node * DIM) + q);
    float a0 = bf16_to_f32(hv.x) * sw;
    float a1 = bf16_to_f32(hv.y) * sw;
    float a2 = bf16_to_f32(hv.z) * sw;
    float a3 = bf16_to_f32(hv.w) * sw;

    int e = base;
    for (; e + 7 < end; e += 8) {
        int s[8]; float w[8]; ushort4 v[8];
#pragma unroll
        for (int i = 0; i < 8; ++i) { s[i] = csr_src[e + i]; w[i] = csr_norm[e + i]; }
#pragma unroll
        for (int i = 0; i < 8; ++i) v[i] = *((const ushort4*)(Hb + (size_t)s[i] * DIM) + q);
#pragma unroll
        for (int i = 0; i < 8; ++i) {
            a0 += bf16_to_f32(v[i].x) * w[i];
            a1 += bf16_to_f32(v[i].y) * w[i];
            a2 += bf16_to_f32(v[i].z) * w[i];
            a3 += bf16_to_f32(v[i].w) * w[i];
        }
    }
    for (; e < end; ++e) {
        int si = csr_src[e];
        float wi = csr_norm[e];
        ushort4 vi = *((const ushort4*)(Hb + (size_t)si * DIM) + q);
        a0 += bf16_to_f32(vi.x) * wi;
        a1 += bf16_to_f32(vi.y) * wi;
        a2 += bf16_to_f32(vi.z) * wi;
        a3 += bf16_to_f32(vi.w) * wi;
    }
    *((float4*)(z + (size_t)node * DIM) + q) = make_float4(a0, a1, a2, a3);
    *(ushort4*)(ZPKp + dst) = make_ushort4(bf16_rne(a0), bf16_rne(a1), bf16_rne(a2), bf16_rne(a3));
}

// ================= fused GEMM2 || GEMM3 (both read ZPKp; GEMM2 relus A in-reg) =================

__global__ __launch_bounds__(256, 3) void gemm23_kernel(
    const short* __restrict__ ZPKp, const short* __restrict__ WT2,
    const float* __restrict__ b2, unsigned short* __restrict__ Hb,
    const short* __restrict__ WTp1,
    const float* __restrict__ bp1, short* __restrict__ APKp1)
{
    __shared__ short As[3][4096];
    __shared__ short Bs[3][4096];
    const int bid = blockIdx.x;
    f32x4 acc[4][4];
    int rb, cb, wr, wc;
    if (bid < GBLKS) {
        gemm128_core<true>(ZPKp, WT2, bid, acc, As, Bs, rb, cb, wr, wc);   // relu(z)@W2
        epi128_bf16(acc, b2, Hb, rb, cb, wr, wc);
    } else {
        gemm128_core<false>(ZPKp, WTp1, bid - GBLKS, acc, As, Bs, rb, cb, wr, wc);  // z@Wp1
        epi128_pack(acc, bp1, APKp1, rb, cb, wr, wc);
    }
}

// ================= aggregate2 (2 nodes/block, ushort4 gathers) =================

__global__ __launch_bounds__(256) void agg2_kernel(
    const unsigned short* __restrict__ Hb, const float* __restrict__ dis,
    const int* __restrict__ deg, const int* __restrict__ csr_src,
    const float* __restrict__ csr_norm, float* __restrict__ out)
{
    const int node = blockIdx.x * 2 + (threadIdx.x >> 7);
    const int q = threadIdx.x & 127;

    const int base = node * MAXDEG;
    const int end  = base + deg[node];
    const float dn = dis[node];
    const float sw = dn * dn;

    ushort4 hv = *((const ushort4*)(Hb + (size_t)node * DIM) + q);
    float a0 = bf16_to_f32(hv.x) * sw;
    float a1 = bf16_to_f32(hv.y) * sw;
    float a2 = bf16_to_f32(hv.z) * sw;
    float a3 = bf16_to_f32(hv.w) * sw;

    int e = base;
    for (; e + 7 < end; e += 8) {
        int s[8]; float w[8]; ushort4 v[8];
#pragma unroll
        for (int i = 0; i < 8; ++i) { s[i] = csr_src[e + i]; w[i] = csr_norm[e + i]; }
#pragma unroll
        for (int i = 0; i < 8; ++i) v[i] = *((const ushort4*)(Hb + (size_t)s[i] * DIM) + q);
#pragma unroll
        for (int i = 0; i < 8; ++i) {
            a0 += bf16_to_f32(v[i].x) * w[i];
            a1 += bf16_to_f32(v[i].y) * w[i];
            a2 += bf16_to_f32(v[i].z) * w[i];
            a3 += bf16_to_f32(v[i].w) * w[i];
        }
    }
    for (; e < end; ++e) {
        int si = csr_src[e];
        float wi = csr_norm[e];
        ushort4 vi = *((const ushort4*)(Hb + (size_t)si * DIM) + q);
        a0 += bf16_to_f32(vi.x) * wi;
        a1 += bf16_to_f32(vi.y) * wi;
        a2 += bf16_to_f32(vi.z) * wi;
        a3 += bf16_to_f32(vi.w) * wi;
    }
    *((float4*)(out + (size_t)node * DIM) + q) = make_float4(a0, a1, a2, a3);
}

// ================= GEMM4 =================

__global__ __launch_bounds__(256, 3) void gemm4_kernel(
    const short* __restrict__ APKp1, const short* __restrict__ WTp2,
    const float* __restrict__ bp2, float* __restrict__ proj)
{
    __shared__ short As[3][4096];
    __shared__ short Bs[3][4096];
    f32x4 acc[4][4];
    int rb, cb, wr, wc;
    gemm128_core<false>(APKp1, WTp2, blockIdx.x, acc, As, Bs, rb, cb, wr, wc);
    epi128_f32<false>(acc, bp2, proj, rb, cb, wr, wc);
}

// ================= launch =================

extern "C" void kernel_launch(void* const* d_in, const int* in_sizes, int n_in,
                              void* d_out, int out_size, void* d_ws, size_t ws_size,
                              hipStream_t stream) {
    const float* x   = (const float*)d_in[0];
    const int*   ei  = (const int*)d_in[1];
    const float* W1  = (const float*)d_in[2];
    const float* b1  = (const float*)d_in[3];
    const float* W2  = (const float*)d_in[4];
    const float* b2  = (const float*)d_in[5];
    const float* Wp1 = (const float*)d_in[6];
    const float* bp1 = (const float*)d_in[7];
    const float* Wp2 = (const float*)d_in[8];
    const float* bp2 = (const float*)d_in[9];

    float* out  = (float*)d_out;
    float* z    = out + (size_t)N_NODES * DIM;
    float* proj = z   + (size_t)N_NODES * DIM;

    char* ws = (char*)d_ws;
    size_t off = 0;
    auto walloc = [&](size_t bytes) -> void* {
        void* p = ws + off;
        off = (off + bytes + 255) & ~(size_t)255;
        return p;
    };
    const size_t PK_SHORTS = (size_t)RBT * 16 * 2048;   // 10.35 MB
    unsigned short* Hb = (unsigned short*)walloc((size_t)N_NODES * DIM * sizeof(unsigned short));
    short* APKx  = (short*)walloc(PK_SHORTS * sizeof(short));
    short* ZPKp  = (short*)walloc(PK_SHORTS * sizeof(short));
    short* APKp1 = (short*)walloc(PK_SHORTS * sizeof(short));
    short* WT1  = (short*)walloc((size_t)8 * 16 * 2048 * sizeof(short));
    short* WT2  = (short*)walloc((size_t)8 * 16 * 2048 * sizeof(short));
    short* WTp1 = (short*)walloc((size_t)8 * 16 * 2048 * sizeof(short));
    short* WTp2 = (short*)walloc((size_t)8 * 16 * 2048 * sizeof(short));
    int*   deg      = (int*)  walloc(N_NODES * sizeof(int));
    int*   cursor   = (int*)  walloc(N_NODES * sizeof(int));
    float* dis      = (float*)walloc(N_NODES * sizeof(float));
    int*   csr_src  = (int*)  walloc((size_t)N_NODES * MAXDEG * sizeof(int));
    float* csr_norm = (float*)walloc((size_t)N_NODES * MAXDEG * sizeof(float));

    const dim3 blk(256);

    hipMemsetAsync(deg, 0, N_NODES * sizeof(int), stream);
    prep_kernel<<<dim3(512 + PAKBLKS + EBLKS), blk, 0, stream>>>(
        W1, W2, Wp1, Wp2, WT1, WT2, WTp1, WTp2, x, APKx, ei, deg);
    deg2dis_kernel<<<dim3((N_NODES + 255) / 256), blk, 0, stream>>>(deg, dis, cursor, N_NODES);

    gemm1_scatter_kernel<<<dim3(GBLKS + EBLKS), blk, 0, stream>>>(
        APKx, WT1, b1, Hb, ei, dis, cursor, csr_src, csr_norm);
    agg1_pack_kernel<<<dim3(RB128 * 64), blk, 0, stream>>>(
        Hb, dis, deg, csr_src, csr_norm, z, ZPKp);
    gemm23_kernel<<<dim3(2 * GBLKS), blk, 0, stream>>>(
        ZPKp, WT2, b2, Hb, WTp1, bp1, APKp1);
    agg2_kernel<<<dim3(N_NODES / 2), blk, 0, stream>>>(
        Hb, dis, deg, csr_src, csr_norm, out);
    gemm4_kernel<<<dim3(GBLKS), blk, 0, stream>>>(APKp1, WTp2, bp2, proj);
}

// Round 22
// 137.150 us; speedup vs baseline: 1.2132x; 1.0682x over previous
//
#include <hip/hip_runtime.h>
#include <stddef.h>

#define N_NODES 10000
#define N_EDGES 160000
#define DIM     512
#define RBT     158           // 64-row tiles incl. one zero pad tile (10112 rows)
#define GB64    (RBT * 4)     // 632 gemm blocks (64x128 tiles, 4 col-groups of 128)
#define EBLKS   625
#define PAKBLKS (RBT * 16)    // 2528
#define MAXDEG  64            // P(Binomial(160000,1e-4) >= 64) ~ 1e-19 -- structurally safe

typedef short bf16x8 __attribute__((ext_vector_type(8)));
typedef float f32x4  __attribute__((ext_vector_type(4)));

__device__ inline unsigned short bf16_rne(float f) {
    unsigned u = __builtin_bit_cast(unsigned, f);
    u += 0x7FFF + ((u >> 16) & 1);
    return (unsigned short)(u >> 16);
}
__device__ inline float bf16_to_f32(unsigned short h) {
    unsigned u = ((unsigned)h) << 16;
    return __builtin_bit_cast(float, u);
}

__device__ inline void gld_lds16(const void* g, void* lds) {
    __builtin_amdgcn_global_load_lds(
        (const __attribute__((address_space(1))) void*)g,
        (__attribute__((address_space(3))) void*)lds, 16, 0, 0);
}

// bf16 relu on packed shorts: bf16 sign bit == int16 sign => max_i16(v,0) is exact relu
__device__ __forceinline__ bf16x8 relu_pk(bf16x8 v) {
    bf16x8 r;
#pragma unroll
    for (int i = 0; i < 8; ++i) r[i] = (v[i] < (short)0) ? (short)0 : v[i];
    return r;
}

// ================= merged prep: pack 4 weights + pack x + count deg =================
// deg zeroed by hipMemsetAsync before this kernel.
// Tile layout (shorts): [blk64][kt 16][idx 64][k 32], 2048/tile; XOR perm baked.

__global__ __launch_bounds__(256) void prep_kernel(
    const float* __restrict__ W1, const float* __restrict__ W2,
    const float* __restrict__ Wp1, const float* __restrict__ Wp2,
    short* __restrict__ T1, short* __restrict__ T2,
    short* __restrict__ Tp1, short* __restrict__ Tp2,
    const float* __restrict__ X, short* __restrict__ APKx,
    const int* __restrict__ ei, int* __restrict__ deg)
{
    const int bid = blockIdx.x;
    if (bid < 512) {                       // ---- pack weights ----
        const int wsel = bid >> 7;
        const float* W = (wsel == 0) ? W1 : (wsel == 1) ? W2 : (wsel == 2) ? Wp1 : Wp2;
        short* WT      = (wsel == 0) ? T1 : (wsel == 1) ? T2 : (wsel == 2) ? Tp1 : Tp2;
        int id = (bid & 127) * 256 + threadIdx.x;
        int n  = id & 511;
        int kc = id >> 9;
        int colblk = n >> 6, col = n & 63;
        int kt = kc >> 2, kq = kc & 3;
        short hi[8];
#pragma unroll
        for (int j = 0; j < 8; ++j)
            hi[j] = (short)bf16_rne(W[(size_t)(kc * 8 + j) * 512 + n]);
        size_t base = (size_t)(colblk * 16 + kt) * 2048 + col * 32 + ((kq ^ ((col >> 1) & 3)) << 3);
        *(int4*)(WT + base) = *(const int4*)hi;
    } else if (bid < 512 + PAKBLKS) {      // ---- pack x ----
        const int pb = bid - 512;
        const int kt = pb & 15;
        const int rb = pb >> 4;
        const int t  = threadIdx.x;
        const int r  = t >> 2;
        const int kq = t & 3;
        const int row = rb * 64 + r;
        float v[8] = {};
        if (row < N_NODES) {
            float4 a = *(const float4*)(X + (size_t)row * 512 + kt * 32 + kq * 8);
            float4 b = *(const float4*)(X + (size_t)row * 512 + kt * 32 + kq * 8 + 4);
            v[0]=a.x; v[1]=a.y; v[2]=a.z; v[3]=a.w; v[4]=b.x; v[5]=b.y; v[6]=b.z; v[7]=b.w;
        }
        short hi[8];
#pragma unroll
        for (int j = 0; j < 8; ++j) hi[j] = (short)bf16_rne(v[j]);
        size_t base = (size_t)(rb * 16 + kt) * 2048 + r * 32 + ((kq ^ ((r >> 1) & 3)) << 3);
        *(int4*)(APKx + base) = *(const int4*)hi;
    } else {                               // ---- count deg ----
        int e = (bid - 512 - PAKBLKS) * 256 + threadIdx.x;
        if (e < N_EDGES) atomicAdd(&deg[ei[N_EDGES + e]], 1);
    }
}

// ================= deg -> dis, zero cursor =================

__global__ __launch_bounds__(256) void deg2dis_kernel(const int* __restrict__ deg,
                                                      float* __restrict__ dis,
                                                      int* __restrict__ cursor, int n) {
    int i = blockIdx.x * 256 + threadIdx.x;
    if (i < n) {
        dis[i] = rsqrtf((float)(deg[i] + 1));
        cursor[i] = 0;
    }
}

// ================= 64x128 bf16 LDS-staged GEMM core =================
// 4 waves, each owns a 64x32 output slice (acc[4][2]); 3-deep circular buffer,
// ONE barrier per kt, counted vmcnt(3). 632 blocks/GEMM (~2.5/CU) so co-resident
// blocks absorb barrier drains. cb-fastest XCD map keeps each A row-tile in one XCD's L2.

__device__ __forceinline__ void map_block64(int bid, int& rb, int& cb) {
    const int q = GB64 / 8;       // 79 (exact)
    int xcd = bid & 7;
    int idx = bid >> 3;
    int L = xcd * q + idx;
    rb = L >> 2;                  // cb fastest -> A reuse within XCD
    cb = L & 3;
}

template<bool RELU_A>
__device__ __forceinline__ void gemm64_core(
    const short* __restrict__ Apk, const short* __restrict__ Wpk,
    int bid, f32x4 (&acc)[4][2],
    short (*As)[2048], short (*Bs)[4096],   // [3][...]
    int& rb, int& cb, int& w)
{
    map_block64(bid, rb, cb);
    const int tid = threadIdx.x;
    w = tid >> 6;                 // 0..3: col slice of 32
    const int lane = tid & 63;
    const int l15 = lane & 15, kg = lane >> 4;
    const int kso = ((kg ^ ((l15 >> 1) & 3)) << 3);
    const int wofs = w * 1024;    // wave-uniform dest offset within each 4KB chunk

    const char* At  = (const char*)(Apk + (size_t)rb * 16 * 2048);
    const char* Bt0 = (const char*)(Wpk + (size_t)(cb * 2)     * 16 * 2048);
    const char* Bt1 = (const char*)(Wpk + (size_t)(cb * 2 + 1) * 16 * 2048);

#pragma unroll
    for (int i = 0; i < 4; ++i)
#pragma unroll
        for (int j = 0; j < 2; ++j) acc[i][j] = (f32x4){0.f, 0.f, 0.f, 0.f};

    // 3 glds/thread/stage: A (4KB), B0 (4KB), B1 (4KB)
    auto stage = [&](int buf, int kt) {
        const int go = kt * 4096 + tid * 16;
        char* ad = (char*)&As[buf][0];
        char* bd = (char*)&Bs[buf][0];
        gld_lds16(At  + go, ad + wofs);
        gld_lds16(Bt0 + go, bd + wofs);
        gld_lds16(Bt1 + go, bd + 4096 + wofs);
    };

    stage(0, 0);
    stage(1, 1);

    const int bchunk = (w >> 1) * 2048;         // colblk half
    const int bcol0  = (w & 1) * 32;            // col offset within half

#pragma unroll
    for (int kt = 0; kt < 16; ++kt) {
        const int buf = kt % 3;
        if (kt < 15) {
            asm volatile("s_waitcnt vmcnt(3)" ::: "memory");   // tile kt landed; kt+1 in flight
        } else {
            asm volatile("s_waitcnt vmcnt(0)" ::: "memory");
        }
        __builtin_amdgcn_s_barrier();
        __builtin_amdgcn_sched_barrier(0);
        if (kt < 14) stage((kt + 2) % 3, kt + 2);

        const short* as = &As[buf][0];
        const short* bs = &Bs[buf][bchunk];
        bf16x8 af[4], bf[2];
#pragma unroll
        for (int m = 0; m < 4; ++m) {
            af[m] = *(const bf16x8*)&as[(m * 16 + l15) * 32 + kso];
            if (RELU_A) af[m] = relu_pk(af[m]);
        }
#pragma unroll
        for (int n = 0; n < 2; ++n)
            bf[n] = *(const bf16x8*)&bs[(bcol0 + n * 16 + l15) * 32 + kso];
#pragma unroll
        for (int m = 0; m < 4; ++m)
#pragma unroll
            for (int n = 0; n < 2; ++n)
                acc[m][n] = __builtin_amdgcn_mfma_f32_16x16x32_bf16(af[m], bf[n], acc[m][n], 0, 0, 0);
    }
}

// ---- epilogues (each wave writes its 64x32 slice) ----

template<bool RELU_OUT>
__device__ __forceinline__ void epi64_f32(f32x4 (&acc)[4][2], const float* bias,
                                          float* C, int rb, int cb, int w) {
    const int lane = threadIdx.x & 63;
    const int l15 = lane & 15, kg = lane >> 4;
    const int cbase = (cb * 2 + (w >> 1)) * 64 + (w & 1) * 32;
#pragma unroll
    for (int n = 0; n < 2; ++n) {
        int c = cbase + n * 16 + l15;
        float bv = bias[c];
#pragma unroll
        for (int m = 0; m < 4; ++m) {
            int r0 = rb * 64 + m * 16 + kg * 4;
#pragma unroll
            for (int j = 0; j < 4; ++j) {
                int row = r0 + j;
                if (row < N_NODES) {
                    float v = acc[m][n][j] + bv;
                    if (RELU_OUT) v = fmaxf(v, 0.f);
                    C[(size_t)row * 512 + c] = v;
                }
            }
        }
    }
}

__device__ __forceinline__ void epi64_bf16(f32x4 (&acc)[4][2], const float* bias,
                                           unsigned short* C, int rb, int cb, int w) {
    const int lane = threadIdx.x & 63;
    const int l15 = lane & 15, kg = lane >> 4;
    const int cbase = (cb * 2 + (w >> 1)) * 64 + (w & 1) * 32;
#pragma unroll
    for (int n = 0; n < 2; ++n) {
        int c = cbase + n * 16 + l15;
        float bv = bias[c];
#pragma unroll
        for (int m = 0; m < 4; ++m) {
            int r0 = rb * 64 + m * 16 + kg * 4;
#pragma unroll
            for (int j = 0; j < 4; ++j) {
                int row = r0 + j;
                if (row < N_NODES)
                    C[(size_t)row * 512 + c] = bf16_rne(acc[m][n][j] + bv);
            }
        }
    }
}

// relu(acc+bias) -> packed bf16 A-layout for the next GEMM (pad rows written zero)
__device__ __forceinline__ void epi64_pack(f32x4 (&acc)[4][2], const float* bias,
                                           short* Cpk, int rb, int cb, int w) {
    const int lane = threadIdx.x & 63;
    const int l15 = lane & 15, kg = lane >> 4;
    const int cbase = (cb * 2 + (w >> 1)) * 64 + (w & 1) * 32;
#pragma unroll
    for (int n = 0; n < 2; ++n) {
        int c = cbase + n * 16 + l15;    // = next-gemm k index
        int kt_n = c >> 5, kk = c & 31, kgn = kk >> 3, kj = kk & 7;
        float bv = bias[c];
#pragma unroll
        for (int m = 0; m < 4; ++m) {
#pragma unroll
            for (int j = 0; j < 4; ++j) {
                int grow = rb * 64 + m * 16 + kg * 4 + j;   // <= 10111
                float v = (grow < N_NODES) ? fmaxf(acc[m][n][j] + bv, 0.f) : 0.f;
                int rt = grow >> 6, rl = grow & 63;
                size_t dst = (size_t)(rt * 16 + kt_n) * 2048 + rl * 32
                           + ((kgn ^ ((rl >> 1) & 3)) << 3) + kj;
                Cpk[dst] = (short)bf16_rne(v);
            }
        }
    }
}

// ================= fused GEMM1 + scatter (fixed-stride CSR) =================

__global__ __launch_bounds__(256, 4) void gemm1_scatter_kernel(
    const short* __restrict__ APKx, const short* __restrict__ WT1,
    const float* __restrict__ b1, unsigned short* __restrict__ Hb,
    const int* __restrict__ ei, const float* __restrict__ dis,
    int* __restrict__ cursor,
    int* __restrict__ csr_src, float* __restrict__ csr_norm)
{
    __shared__ short As[3][2048];
    __shared__ short Bs[3][4096];
    const int bid = blockIdx.x;
    if (bid >= GB64) {
        int e = (bid - GB64) * 256 + threadIdx.x;
        if (e < N_EDGES) {
            int s = ei[e];
            int d = ei[N_EDGES + e];
            int slot = d * MAXDEG + atomicAdd(&cursor[d], 1);
            csr_src[slot]  = s;
            csr_norm[slot] = dis[s] * dis[d];
        }
        return;
    }
    f32x4 acc[4][2];
    int rb, cb, w;
    gemm64_core<false>(APKx, WT1, bid, acc, As, Bs, rb, cb, w);
    epi64_bf16(acc, b1, Hb, rb, cb, w);
}

// ================= aggregate1 + fused z-pack (2 nodes/block, ushort4 gathers) =================

__global__ __launch_bounds__(256) void agg1_pack_kernel(
    const unsigned short* __restrict__ Hb,
    const float* __restrict__ dis,
    const int* __restrict__ deg,
    const int* __restrict__ csr_src,
    const float* __restrict__ csr_norm,
    float* __restrict__ z,
    short* __restrict__ ZPKp)
{
    const int node = blockIdx.x * 2 + (threadIdx.x >> 7);
    const int q = threadIdx.x & 127;
    const int f0 = q * 4;
    const int kt = f0 >> 5, kq = (f0 >> 3) & 3, j = f0 & 7;   // j in {0,4}
    const int rb = node >> 6, r = node & 63;
    const size_t dst = (size_t)(rb * 16 + kt) * 2048 + r * 32 + ((kq ^ ((r >> 1) & 3)) << 3) + j;

    if (node >= N_NODES) {   // zero pad rows
        *(ushort4*)(ZPKp + dst) = make_ushort4(0, 0, 0, 0);
        return;
    }

    const int base = node * MAXDEG;
    const int end  = base + deg[node];
    const float dn = dis[node];
    const float sw = dn * dn;

    ushort4 hv = *((const ushort4*)(Hb + (size_t)node * DIM) + q);
    float a0 = bf16_to_f32(hv.x) * sw;
    float a1 = bf16_to_f32(hv.y) * sw;
    float a2 = bf16_to_f32(hv.z) * sw;
    float a3 = bf16_to_f32(hv.w) * sw;

    int e = base;
    for (; e + 7 < end; e += 8) {
        int s[8]; float w[8]; ushort4 v[8];
#pragma unroll
        for (int i = 0; i < 8; ++i) { s[i] = csr_src[e + i]; w[i] = csr_norm[e + i]; }
#pragma unroll
        for (int i = 0; i < 8; ++i) v[i] = *((const ushort4*)(Hb + (size_t)s[i] * DIM) + q);
#pragma unroll
        for (int i = 0; i < 8; ++i) {
            a0 += bf16_to_f32(v[i].x) * w[i];
            a1 += bf16_to_f32(v[i].y) * w[i];
            a2 += bf16_to_f32(v[i].z) * w[i];
            a3 += bf16_to_f32(v[i].w) * w[i];
        }
    }
    for (; e < end; ++e) {
        int si = csr_src[e];
        float wi = csr_norm[e];
        ushort4 vi = *((const ushort4*)(Hb + (size_t)si * DIM) + q);
        a0 += bf16_to_f32(vi.x) * wi;
        a1 += bf16_to_f32(vi.y) * wi;
        a2 += bf16_to_f32(vi.z) * wi;
        a3 += bf16_to_f32(vi.w) * wi;
    }
    *((float4*)(z + (size_t)node * DIM) + q) = make_float4(a0, a1, a2, a3);
    *(ushort4*)(ZPKp + dst) = make_ushort4(bf16_rne(a0), bf16_rne(a1), bf16_rne(a2), bf16_rne(a3));
}

// ================= fused GEMM2 || GEMM3 (both read ZPKp; GEMM2 relus A in-reg) =================

__global__ __launch_bounds__(256, 4) void gemm23_kernel(
    const short* __restrict__ ZPKp, const short* __restrict__ WT2,
    const float* __restrict__ b2, unsigned short* __restrict__ Hb,
    const short* __restrict__ WTp1,
    const float* __restrict__ bp1, short* __restrict__ APKp1)
{
    __shared__ short As[3][2048];
    __shared__ short Bs[3][4096];
    const int bid = blockIdx.x;
    f32x4 acc[4][2];
    int rb, cb, w;
    if (bid < GB64) {
        gemm64_core<true>(ZPKp, WT2, bid, acc, As, Bs, rb, cb, w);   // relu(z)@W2
        epi64_bf16(acc, b2, Hb, rb, cb, w);
    } else {
        gemm64_core<false>(ZPKp, WTp1, bid - GB64, acc, As, Bs, rb, cb, w);  // z@Wp1
        epi64_pack(acc, bp1, APKp1, rb, cb, w);
    }
}

// ================= aggregate2 (2 nodes/block, ushort4 gathers) =================

__global__ __launch_bounds__(256) void agg2_kernel(
    const unsigned short* __restrict__ Hb, const float* __restrict__ dis,
    const int* __restrict__ deg, const int* __restrict__ csr_src,
    const float* __restrict__ csr_norm, float* __restrict__ out)
{
    const int node = blockIdx.x * 2 + (threadIdx.x >> 7);
    const int q = threadIdx.x & 127;

    const int base = node * MAXDEG;
    const int end  = base + deg[node];
    const float dn = dis[node];
    const float sw = dn * dn;

    ushort4 hv = *((const ushort4*)(Hb + (size_t)node * DIM) + q);
    float a0 = bf16_to_f32(hv.x) * sw;
    float a1 = bf16_to_f32(hv.y) * sw;
    float a2 = bf16_to_f32(hv.z) * sw;
    float a3 = bf16_to_f32(hv.w) * sw;

    int e = base;
    for (; e + 7 < end; e += 8) {
        int s[8]; float w[8]; ushort4 v[8];
#pragma unroll
        for (int i = 0; i < 8; ++i) { s[i] = csr_src[e + i]; w[i] = csr_norm[e + i]; }
#pragma unroll
        for (int i = 0; i < 8; ++i) v[i] = *((const ushort4*)(Hb + (size_t)s[i] * DIM) + q);
#pragma unroll
        for (int i = 0; i < 8; ++i) {
            a0 += bf16_to_f32(v[i].x) * w[i];
            a1 += bf16_to_f32(v[i].y) * w[i];
            a2 += bf16_to_f32(v[i].z) * w[i];
            a3 += bf16_to_f32(v[i].w) * w[i];
        }
    }
    for (; e < end; ++e) {
        int si = csr_src[e];
        float wi = csr_norm[e];
        ushort4 vi = *((const ushort4*)(Hb + (size_t)si * DIM) + q);
        a0 += bf16_to_f32(vi.x) * wi;
        a1 += bf16_to_f32(vi.y) * wi;
        a2 += bf16_to_f32(vi.z) * wi;
        a3 += bf16_to_f32(vi.w) * wi;
    }
    *((float4*)(out + (size_t)node * DIM) + q) = make_float4(a0, a1, a2, a3);
}

// ================= GEMM4 =================

__global__ __launch_bounds__(256, 4) void gemm4_kernel(
    const short* __restrict__ APKp1, const short* __restrict__ WTp2,
    const float* __restrict__ bp2, float* __restrict__ proj)
{
    __shared__ short As[3][2048];
    __shared__ short Bs[3][4096];
    f32x4 acc[4][2];
    int rb, cb, w;
    gemm64_core<false>(APKp1, WTp2, blockIdx.x, acc, As, Bs, rb, cb, w);
    epi64_f32<false>(acc, bp2, proj, rb, cb, w);
}

// ================= launch =================

extern "C" void kernel_launch(void* const* d_in, const int* in_sizes, int n_in,
                              void* d_out, int out_size, void* d_ws, size_t ws_size,
                              hipStream_t stream) {
    const float* x   = (const float*)d_in[0];
    const int*   ei  = (const int*)d_in[1];
    const float* W1  = (const float*)d_in[2];
    const float* b1  = (const float*)d_in[3];
    const float* W2  = (const float*)d_in[4];
    const float* b2  = (const float*)d_in[5];
    const float* Wp1 = (const float*)d_in[6];
    const float* bp1 = (const float*)d_in[7];
    const float* Wp2 = (const float*)d_in[8];
    const float* bp2 = (const float*)d_in[9];

    float* out  = (float*)d_out;
    float* z    = out + (size_t)N_NODES * DIM;
    float* proj = z   + (size_t)N_NODES * DIM;

    char* ws = (char*)d_ws;
    size_t off = 0;
    auto walloc = [&](size_t bytes) -> void* {
        void* p = ws + off;
        off = (off + bytes + 255) & ~(size_t)255;
        return p;
    };
    const size_t PK_SHORTS = (size_t)RBT * 16 * 2048;   // 10.35 MB
    unsigned short* Hb = (unsigned short*)walloc((size_t)N_NODES * DIM * sizeof(unsigned short));
    short* APKx  = (short*)walloc(PK_SHORTS * sizeof(short));
    short* ZPKp  = (short*)walloc(PK_SHORTS * sizeof(short));
    short* APKp1 = (short*)walloc(PK_SHORTS * sizeof(short));
    short* WT1  = (short*)walloc((size_t)8 * 16 * 2048 * sizeof(short));
    short* WT2  = (short*)walloc((size_t)8 * 16 * 2048 * sizeof(short));
    short* WTp1 = (short*)walloc((size_t)8 * 16 * 2048 * sizeof(short));
    short* WTp2 = (short*)walloc((size_t)8 * 16 * 2048 * sizeof(short));
    int*   deg      = (int*)  walloc(N_NODES * sizeof(int));
    int*   cursor   = (int*)  walloc(N_NODES * sizeof(int));
    float* dis      = (float*)walloc(N_NODES * sizeof(float));
    int*   csr_src  = (int*)  walloc((size_t)N_NODES * MAXDEG * sizeof(int));
    float* csr_norm = (float*)walloc((size_t)N_NODES * MAXDEG * sizeof(float));

    const dim3 blk(256);

    hipMemsetAsync(deg, 0, N_NODES * sizeof(int), stream);
    prep_kernel<<<dim3(512 + PAKBLKS + EBLKS), blk, 0, stream>>>(
        W1, W2, Wp1, Wp2, WT1, WT2, WTp1, WTp2, x, APKx, ei, deg);
    deg2dis_kernel<<<dim3((N_NODES + 255) / 256), blk, 0, stream>>>(deg, dis, cursor, N_NODES);

    gemm1_scatter_kernel<<<dim3(GB64 + EBLKS), blk, 0, stream>>>(
        APKx, WT1, b1, Hb, ei, dis, cursor, csr_src, csr_norm);
    agg1_pack_kernel<<<dim3(RBT * 32), blk, 0, stream>>>(
        Hb, dis, deg, csr_src, csr_norm, z, ZPKp);
    gemm23_kernel<<<dim3(2 * GB64), blk, 0, stream>>>(
        ZPKp, WT2, b2, Hb, WTp1, bp1, APKp1);
    agg2_kernel<<<dim3(N_NODES / 2), blk, 0, stream>>>(
        Hb, dis, deg, csr_src, csr_norm, out);
    gemm4_kernel<<<dim3(GB64), blk, 0, stream>>>(APKp1, WTp2, bp2, proj);
}